// Round 6
// baseline (313.482 us; speedup 1.0000x reference)
//
#include <hip/hip_runtime.h>

typedef __attribute__((ext_vector_type(8))) __bf16 bf16x8;
typedef __attribute__((ext_vector_type(4))) __bf16 bf16x4;
typedef __attribute__((ext_vector_type(4))) float floatx4;

#define MFMA16x16x32 __builtin_amdgcn_mfma_f32_16x16x32_bf16

// async 16B/lane global->LDS; LDS dest = wave-uniform base + lane*16.
__device__ __forceinline__ void async_load16(const void* g, void* l) {
  __builtin_amdgcn_global_load_lds((const __attribute__((address_space(1))) void*)g,
                                   (__attribute__((address_space(3))) void*)l, 16, 0, 0);
}

// ---------------- merged cast fp32 -> bf16 for all 5 inputs ----------------
__global__ __launch_bounds__(256) void cast_all_kernel(const float* __restrict__ x,
                                                       const float* __restrict__ wq,
                                                       const float* __restrict__ wk,
                                                       const float* __restrict__ wv,
                                                       const float* __restrict__ wo,
                                                       __bf16* __restrict__ dst) {
  int i = blockIdx.x * blockDim.x + threadIdx.x;  // float4 units
  const float* src;
  int off;
  if (i < 2097152)      { src = x;  off = 0; }
  else if (i < 3145728) { src = wq; off = 2097152; }
  else if (i < 3407872) { src = wk; off = 3145728; }
  else if (i < 3670016) { src = wv; off = 3407872; }
  else                  { src = wo; off = 3670016; }
  float4 v = ((const float4*)src)[i - off];
  bf16x4 o;
  o[0] = (__bf16)v.x; o[1] = (__bf16)v.y; o[2] = (__bf16)v.z; o[3] = (__bf16)v.w;
  *(bf16x4*)(dst + (size_t)i * 4) = o;
}

// ---------------- GEMM: C(M,N) = A(M,K) @ B(N,K)^T, bf16 in, m97-style ----------------
// MODE 0: fp32 C store. MODE 1: fused epilogue -> qb (rope), kb (rope), vtg (transposed cast).
template <int MODE>
__global__ __launch_bounds__(256, 3) void gemm_bt(const __bf16* __restrict__ A,
                                                  const __bf16* __restrict__ Bw,
                                                  float* __restrict__ C,
                                                  const float* __restrict__ cs,
                                                  const float* __restrict__ sn,
                                                  __bf16* __restrict__ qb,
                                                  __bf16* __restrict__ kb,
                                                  __bf16* __restrict__ vtg,
                                                  int M, int N, int K) {
  __shared__ __bf16 As[128][64];
  __shared__ __bf16 Bs[128][64];
  const int tid = threadIdx.x;
  const int wave = tid >> 6, lane = tid & 63;
  const int quad = lane >> 4, l16 = lane & 15;
  const int wm = (wave >> 1) * 64, wn = (wave & 1) * 64;
  const int row0 = blockIdx.y * 128, col0 = blockIdx.x * 128;
  const int lr = lane >> 3, ls = lane & 7;
  const int segg = ls ^ lr;
  floatx4 acc[4][4] = {};
  const __bf16* Ab = A + (size_t)row0 * K + segg * 8;
  const __bf16* Bb = Bw + (size_t)col0 * K + segg * 8;
  for (int k0 = 0; k0 < K; k0 += 64) {
    __syncthreads();
#pragma unroll
    for (int i = 0; i < 4; i++) {
      int c = wave * 4 + i;
      int r = c * 8 + lr;
      async_load16(Ab + (size_t)r * K + k0, &As[c * 8][0]);
      async_load16(Bb + (size_t)r * K + k0, &Bs[c * 8][0]);
    }
    __syncthreads();
#pragma unroll
    for (int kk = 0; kk < 64; kk += 32) {
      bf16x8 af[4], bfr[4];
#pragma unroll
      for (int mt = 0; mt < 4; mt++) {
        int row = wm + mt * 16 + l16;
        int seg = ((kk >> 3) + quad) ^ (row & 7);
        af[mt] = *(const bf16x8*)&As[row][seg * 8];
      }
#pragma unroll
      for (int nt = 0; nt < 4; nt++) {
        int row = wn + nt * 16 + l16;
        int seg = ((kk >> 3) + quad) ^ (row & 7);
        bfr[nt] = *(const bf16x8*)&Bs[row][seg * 8];
      }
#pragma unroll
      for (int mt = 0; mt < 4; mt++)
#pragma unroll
        for (int nt = 0; nt < 4; nt++)
          acc[mt][nt] = MFMA16x16x32(af[mt], bfr[nt], acc[mt][nt], 0, 0, 0);
    }
  }
  if (MODE == 0) {
#pragma unroll
    for (int mt = 0; mt < 4; mt++)
#pragma unroll
      for (int nt = 0; nt < 4; nt++)
#pragma unroll
        for (int r = 0; r < 4; r++) {
          int row = row0 + wm + mt * 16 + quad * 4 + r;
          int col = col0 + wn + nt * 16 + l16;
          C[(size_t)row * N + col] = acc[mt][nt][r];
        }
  } else {
#pragma unroll
    for (int mt = 0; mt < 4; mt++)
#pragma unroll
      for (int nt = 0; nt < 4; nt++) {
        const int cbase = col0 + wn + nt * 16;  // uniform region per (wave,nt)
        const int c = cbase + l16;
#pragma unroll
        for (int r = 0; r < 4; r++) {
          int row = row0 + wm + mt * 16 + quad * 4 + r;
          int t = row & 2047;
          float v = acc[mt][nt][r];
          float vp = __shfl_xor(v, 1);  // RoPE pair partner (col ^ 1)
          if (cbase < 2048) {           // Q + RoPE
            int i = (c & 127) >> 1;
            float co = cs[t * 64 + i], si = sn[t * 64 + i];
            qb[(size_t)row * 2048 + c] = (__bf16)(v * co + ((c & 1) ? vp : -vp) * si);
          } else if (cbase < 2560) {    // K + RoPE
            int i = (c & 127) >> 1;
            float co = cs[t * 64 + i], si = sn[t * 64 + i];
            kb[(size_t)row * 512 + c - 2048] = (__bf16)(v * co + ((c & 1) ? vp : -vp) * si);
          } else {                      // V: store transposed [d][t]
            int vd = c - 2560;
            vtg[((size_t)(row >> 11) * 512 + vd) * 2048 + t] = (__bf16)v;
          }
        }
      }
  }
}

// ---------------- Flash attention, causal, GQA ----------------
// 512 WGs of 4 waves; each wave owns 32 q rows (2 m-tiles) of head kvh*4+wave.
// K/Vt staged once per WG, shared by 4 heads; each wave amortizes the full
// K/V LDS read over 32 rows (halves LDS traffic vs 16-row waves).
// ids p and p+256 get complementary block counts (constant 33/slot).
__global__ __launch_bounds__(256, 2) void attn_kernel(const __bf16* __restrict__ qb,
                                                      const __bf16* __restrict__ kb,
                                                      const __bf16* __restrict__ vtg,
                                                      __bf16* __restrict__ yb) {
  const int id = blockIdx.x;
  const int q1 = id >> 8;              // 0..1
  const int cc = id & 255;
  const int kvh = cc & 3;
  const int b = (cc >> 2) & 1;
  const int s5 = (cc >> 3) & 31;
  const int tile = q1 ? (63 - s5) : s5;  // bijective over 0..63
  const int tid = threadIdx.x, wave = tid >> 6, lane = tid & 63;
  const int h = kvh * 4 + wave;
  const int quad = lane >> 4, l16 = lane & 15;
  const int q0 = tile * 32;
  __shared__ __bf16 Ks[64][128];      // [key][dim], swizzled segs (16 KB)
  __shared__ __bf16 Vt[128][64];      // [dim][key], swizzled segs (16 KB)
  __shared__ __bf16 Ps[4][2][16][64]; // per-wave, per-m-tile P strip (16 KB)
  const __bf16* kbase = kb + (size_t)b * 2048 * 512 + kvh * 128;
  const __bf16* vbase = vtg + ((size_t)b * 512 + kvh * 128) * 2048;
  const float cexp = 0.1275411391f;  // (1/sqrt(128)) * log2(e)
  const int klr4 = lane >> 4, kls = lane & 15;
  const int vlr8 = lane >> 3, vls = lane & 7;
  bf16x8 qf[2][4];
#pragma unroll
  for (int mt = 0; mt < 2; mt++)
#pragma unroll
    for (int kc = 0; kc < 4; kc++)
      qf[mt][kc] = *(const bf16x8*)(qb + (size_t)(b * 2048 + q0 + mt * 16 + l16) * 2048 +
                                    h * 128 + kc * 32 + quad * 8);
  bf16x8 ones;
#pragma unroll
  for (int j = 0; j < 8; j++) ones[j] = (__bf16)1.0f;
  floatx4 o[2][8] = {};
  floatx4 lsum[2] = {};
  const int nblocks = (tile + 2) >> 1;  // ceil((q0+32)/64)
  for (int it = 0; it < nblocks; it++) {
    const int s0 = it * 64;
    __syncthreads();  // all waves done reading prev Ks/Vt
#pragma unroll
    for (int i = 0; i < 4; i++) {   // stage K: 64 keys x 128 dims
      int ch = wave * 4 + i;
      int row = ch * 4 + klr4;
      int sg = kls ^ (row & 7);
      async_load16(kbase + (size_t)(s0 + row) * 512 + sg * 8, &Ks[ch * 4][0]);
    }
#pragma unroll
    for (int i = 0; i < 4; i++) {   // stage Vt: 128 dims x 64 keys
      int ch = wave * 4 + i;
      int d = ch * 8 + vlr8;
      int sg = vls ^ (d & 7);
      async_load16(vbase + (size_t)d * 2048 + s0 + sg * 8, &Vt[ch * 8][0]);
    }
    __syncthreads();  // staging visible
    // QK^T: 32 q rows x 64 keys (K-frags shared by both m-tiles)
    floatx4 sacc[2][4] = {};
#pragma unroll
    for (int kc = 0; kc < 4; kc++) {
      bf16x8 bfr[4];
#pragma unroll
      for (int nt = 0; nt < 4; nt++) {
        int key = nt * 16 + l16;
        int seg = (kc * 4 + quad) ^ (key & 7);
        bfr[nt] = *(const bf16x8*)&Ks[key][seg * 8];
      }
#pragma unroll
      for (int mt = 0; mt < 2; mt++)
#pragma unroll
        for (int nt = 0; nt < 4; nt++)
          sacc[mt][nt] = MFMA16x16x32(qf[mt][kc], bfr[nt], sacc[mt][nt], 0, 0, 0);
    }
    // P = exp(S*scale), masked on diagonal block(s)
    const bool diag = (it == nblocks - 1);
#pragma unroll
    for (int mt = 0; mt < 2; mt++)
#pragma unroll
      for (int r = 0; r < 4; r++) {
        const int row = quad * 4 + r;
        const int qg = q0 + mt * 16 + row;
#pragma unroll
        for (int nt = 0; nt < 4; nt++) {
          float p = __builtin_exp2f(sacc[mt][nt][r] * cexp);
          if (diag) { int keyg = s0 + nt * 16 + l16; p = (keyg <= qg) ? p : 0.f; }
          int col = nt * 16 + l16;
          Ps[wave][mt][row][(((col >> 3) ^ (row & 7)) << 3) + (col & 7)] = (__bf16)p;
        }
      }
    // P @ V (+ ones for row sums). Same-wave Ps write->read: no barrier.
#pragma unroll
    for (int c2 = 0; c2 < 2; c2++) {
      bf16x8 pa[2];
#pragma unroll
      for (int mt = 0; mt < 2; mt++) {
        int segp = ((c2 * 4 + quad) ^ (l16 & 7)) << 3;
        pa[mt] = *(const bf16x8*)&Ps[wave][mt][l16][segp];
        lsum[mt] = MFMA16x16x32(pa[mt], ones, lsum[mt], 0, 0, 0);
      }
#pragma unroll
      for (int dt = 0; dt < 8; dt++) {
        int row = dt * 16 + l16;
        int seg = (c2 * 4 + quad) ^ (row & 7);
        bf16x8 vf = *(const bf16x8*)&Vt[row][seg * 8];
#pragma unroll
        for (int mt = 0; mt < 2; mt++)
          o[mt][dt] = MFMA16x16x32(pa[mt], vf, o[mt][dt], 0, 0, 0);
      }
    }
  }
#pragma unroll
  for (int mt = 0; mt < 2; mt++) {
    float inv[4];
#pragma unroll
    for (int r = 0; r < 4; r++) inv[r] = 1.f / lsum[mt][r];
#pragma unroll
    for (int dt = 0; dt < 8; dt++)
#pragma unroll
      for (int r = 0; r < 4; r++) {
        int qg = q0 + mt * 16 + quad * 4 + r;
        yb[(size_t)(b * 2048 + qg) * 2048 + h * 128 + dt * 16 + l16] =
            (__bf16)(o[mt][dt][r] * inv[r]);
      }
  }
}

// ---------------- host ----------------
extern "C" void kernel_launch(void* const* d_in, const int* in_sizes, int n_in,
                              void* d_out, int out_size, void* d_ws, size_t ws_size,
                              hipStream_t stream) {
  const float* x  = (const float*)d_in[0];
  const float* fc = (const float*)d_in[1];
  const float* fs = (const float*)d_in[2];
  const float* wq = (const float*)d_in[3];
  const float* wk = (const float*)d_in[4];
  const float* wv = (const float*)d_in[5];
  const float* wo = (const float*)d_in[6];
  float* out = (float*)d_out;
  char* ws = (char*)d_ws;

  __bf16* xb   = (__bf16*)(ws);              // 4096x2048 bf16
  __bf16* wqkv = (__bf16*)(ws + 16777216);   // 3072x2048 bf16 (wq|wk|wv)
  __bf16* wob  = (__bf16*)(ws + 29360128);   // 2048x2048 bf16
  __bf16* qbuf = (__bf16*)(ws + 37748736);   // 4096x2048 bf16 (roped)
  __bf16* kbuf = (__bf16*)(ws + 54525952);   // 4096x512 bf16 (roped)
  __bf16* vtg  = (__bf16*)(ws + 58720256);   // 1024x2048 bf16 (V^T per b,kvh)
  __bf16* ybuf = (__bf16*)(ws + 62914560);   // 4096x2048 bf16

  // one merged cast launch (dst regions contiguous from ws+0)
  cast_all_kernel<<<18432, 256, 0, stream>>>(x, wq, wk, wv, wo, xb);

  // QKV projection with fused RoPE + transposed-V epilogue (M=4096, N=3072, K=2048)
  gemm_bt<1><<<dim3(24, 32), 256, 0, stream>>>(xb, wqkv, nullptr, fc, fs,
                                               qbuf, kbuf, vtg, 4096, 3072, 2048);

  // flash attention: 512 4-wave WGs, 32 q-rows/wave, balanced swizzle
  attn_kernel<<<dim3(512), 256, 0, stream>>>(qbuf, kbuf, vtg, ybuf);

  // output projection: out = y @ wo^T (M=4096, N=2048, K=2048)
  gemm_bt<0><<<dim3(16, 32), 256, 0, stream>>>(ybuf, wob, out, nullptr, nullptr,
                                               nullptr, nullptr, nullptr, 4096, 2048, 2048);
}

// Round 7
// 309.400 us; speedup vs baseline: 1.0132x; 1.0132x over previous
//
#include <hip/hip_runtime.h>

typedef __attribute__((ext_vector_type(8))) __bf16 bf16x8;
typedef __attribute__((ext_vector_type(4))) __bf16 bf16x4;
typedef __attribute__((ext_vector_type(4))) float floatx4;

#define MFMA16x16x32 __builtin_amdgcn_mfma_f32_16x16x32_bf16

// async 16B/lane global->LDS; LDS dest = wave-uniform base + lane*16.
__device__ __forceinline__ void async_load16(const void* g, void* l) {
  __builtin_amdgcn_global_load_lds((const __attribute__((address_space(1))) void*)g,
                                   (__attribute__((address_space(3))) void*)l, 16, 0, 0);
}

// ---------------- merged cast fp32 -> bf16 for all 5 inputs ----------------
__global__ __launch_bounds__(256) void cast_all_kernel(const float* __restrict__ x,
                                                       const float* __restrict__ wq,
                                                       const float* __restrict__ wk,
                                                       const float* __restrict__ wv,
                                                       const float* __restrict__ wo,
                                                       __bf16* __restrict__ dst) {
  int i = blockIdx.x * blockDim.x + threadIdx.x;  // float4 units
  const float* src;
  int off;
  if (i < 2097152)      { src = x;  off = 0; }
  else if (i < 3145728) { src = wq; off = 2097152; }
  else if (i < 3407872) { src = wk; off = 3145728; }
  else if (i < 3670016) { src = wv; off = 3407872; }
  else                  { src = wo; off = 3670016; }
  float4 v = ((const float4*)src)[i - off];
  bf16x4 o;
  o[0] = (__bf16)v.x; o[1] = (__bf16)v.y; o[2] = (__bf16)v.z; o[3] = (__bf16)v.w;
  *(bf16x4*)(dst + (size_t)i * 4) = o;
}

// ---------------- GEMM: C(M,N) = A(M,K) @ B(N,K)^T, bf16 in, m97-style ----------------
// MODE 0: fp32 C store. MODE 1: fused epilogue -> qb (rope), kb (rope), vtg (transposed cast).
template <int MODE>
__global__ __launch_bounds__(256, 3) void gemm_bt(const __bf16* __restrict__ A,
                                                  const __bf16* __restrict__ Bw,
                                                  float* __restrict__ C,
                                                  const float* __restrict__ cs,
                                                  const float* __restrict__ sn,
                                                  __bf16* __restrict__ qb,
                                                  __bf16* __restrict__ kb,
                                                  __bf16* __restrict__ vtg,
                                                  int M, int N, int K) {
  __shared__ __bf16 As[128][64];
  __shared__ __bf16 Bs[128][64];
  const int tid = threadIdx.x;
  const int wave = tid >> 6, lane = tid & 63;
  const int quad = lane >> 4, l16 = lane & 15;
  const int wm = (wave >> 1) * 64, wn = (wave & 1) * 64;
  const int row0 = blockIdx.y * 128, col0 = blockIdx.x * 128;
  const int lr = lane >> 3, ls = lane & 7;
  const int segg = ls ^ lr;
  floatx4 acc[4][4] = {};
  const __bf16* Ab = A + (size_t)row0 * K + segg * 8;
  const __bf16* Bb = Bw + (size_t)col0 * K + segg * 8;
  for (int k0 = 0; k0 < K; k0 += 64) {
    __syncthreads();
#pragma unroll
    for (int i = 0; i < 4; i++) {
      int c = wave * 4 + i;
      int r = c * 8 + lr;
      async_load16(Ab + (size_t)r * K + k0, &As[c * 8][0]);
      async_load16(Bb + (size_t)r * K + k0, &Bs[c * 8][0]);
    }
    __syncthreads();
#pragma unroll
    for (int kk = 0; kk < 64; kk += 32) {
      bf16x8 af[4], bfr[4];
#pragma unroll
      for (int mt = 0; mt < 4; mt++) {
        int row = wm + mt * 16 + l16;
        int seg = ((kk >> 3) + quad) ^ (row & 7);
        af[mt] = *(const bf16x8*)&As[row][seg * 8];
      }
#pragma unroll
      for (int nt = 0; nt < 4; nt++) {
        int row = wn + nt * 16 + l16;
        int seg = ((kk >> 3) + quad) ^ (row & 7);
        bfr[nt] = *(const bf16x8*)&Bs[row][seg * 8];
      }
#pragma unroll
      for (int mt = 0; mt < 4; mt++)
#pragma unroll
        for (int nt = 0; nt < 4; nt++)
          acc[mt][nt] = MFMA16x16x32(af[mt], bfr[nt], acc[mt][nt], 0, 0, 0);
    }
  }
  if (MODE == 0) {
#pragma unroll
    for (int mt = 0; mt < 4; mt++)
#pragma unroll
      for (int nt = 0; nt < 4; nt++)
#pragma unroll
        for (int r = 0; r < 4; r++) {
          int row = row0 + wm + mt * 16 + quad * 4 + r;
          int col = col0 + wn + nt * 16 + l16;
          C[(size_t)row * N + col] = acc[mt][nt][r];
        }
  } else {
#pragma unroll
    for (int mt = 0; mt < 4; mt++)
#pragma unroll
      for (int nt = 0; nt < 4; nt++) {
        const int cbase = col0 + wn + nt * 16;  // uniform region per (wave,nt)
        const int c = cbase + l16;
#pragma unroll
        for (int r = 0; r < 4; r++) {
          int row = row0 + wm + mt * 16 + quad * 4 + r;
          int t = row & 2047;
          float v = acc[mt][nt][r];
          float vp = __shfl_xor(v, 1);  // RoPE pair partner (col ^ 1)
          if (cbase < 2048) {           // Q + RoPE
            int i = (c & 127) >> 1;
            float co = cs[t * 64 + i], si = sn[t * 64 + i];
            qb[(size_t)row * 2048 + c] = (__bf16)(v * co + ((c & 1) ? vp : -vp) * si);
          } else if (cbase < 2560) {    // K + RoPE
            int i = (c & 127) >> 1;
            float co = cs[t * 64 + i], si = sn[t * 64 + i];
            kb[(size_t)row * 512 + c - 2048] = (__bf16)(v * co + ((c & 1) ? vp : -vp) * si);
          } else {                      // V: store transposed [d][t]
            int vd = c - 2560;
            vtg[((size_t)(row >> 11) * 512 + vd) * 2048 + t] = (__bf16)v;
          }
        }
      }
  }
}

// ---------------- Flash attention, causal, GQA; double-buffered K/V ----------------
// 512 WGs of 4 waves; each wave owns 32 q rows (2 m-tiles) of head kvh*4+wave.
// K/Vt double-buffered: prefetch block it+1 issued BEFORE compute on block it;
// ONE barrier per iter (its vmcnt(0) drain lands after ~1300 cyc of compute,
// hiding the DMA latency). Buffer-reuse hazard covered by the previous barrier.
__global__ __launch_bounds__(256, 2) void attn_kernel(const __bf16* __restrict__ qb,
                                                      const __bf16* __restrict__ kb,
                                                      const __bf16* __restrict__ vtg,
                                                      __bf16* __restrict__ yb) {
  const int id = blockIdx.x;
  const int q1 = id >> 8;              // 0..1
  const int cc = id & 255;
  const int kvh = cc & 3;
  const int b = (cc >> 2) & 1;
  const int s5 = (cc >> 3) & 31;
  const int tile = q1 ? (63 - s5) : s5;  // bijective over 0..63
  const int tid = threadIdx.x, wave = tid >> 6, lane = tid & 63;
  const int h = kvh * 4 + wave;
  const int quad = lane >> 4, l16 = lane & 15;
  const int q0 = tile * 32;
  __shared__ __bf16 Ks[2][64][128];      // [buf][key][dim], swizzled (32 KB)
  __shared__ __bf16 Vt[2][128][64];      // [buf][dim][key], swizzled (32 KB)
  __shared__ __bf16 Ps[4][2][16][64];    // per-wave, per-m-tile P strip (16 KB)
  const __bf16* kbase = kb + (size_t)b * 2048 * 512 + kvh * 128;
  const __bf16* vbase = vtg + ((size_t)b * 512 + kvh * 128) * 2048;
  const float cexp = 0.1275411391f;  // (1/sqrt(128)) * log2(e)
  const int klr4 = lane >> 4, kls = lane & 15;
  const int vlr8 = lane >> 3, vls = lane & 7;

  auto stage = [&](int pb, int s0) {
#pragma unroll
    for (int i = 0; i < 4; i++) {   // K: 64 keys x 128 dims
      int ch = wave * 4 + i;
      int row = ch * 4 + klr4;
      int sg = kls ^ (row & 7);
      async_load16(kbase + (size_t)(s0 + row) * 512 + sg * 8, &Ks[pb][ch * 4][0]);
    }
#pragma unroll
    for (int i = 0; i < 4; i++) {   // Vt: 128 dims x 64 keys
      int ch = wave * 4 + i;
      int d = ch * 8 + vlr8;
      int sg = vls ^ (d & 7);
      async_load16(vbase + (size_t)d * 2048 + s0 + sg * 8, &Vt[pb][ch * 8][0]);
    }
  };

  bf16x8 qf[2][4];
#pragma unroll
  for (int mt = 0; mt < 2; mt++)
#pragma unroll
    for (int kc = 0; kc < 4; kc++)
      qf[mt][kc] = *(const bf16x8*)(qb + (size_t)(b * 2048 + q0 + mt * 16 + l16) * 2048 +
                                    h * 128 + kc * 32 + quad * 8);
  bf16x8 ones;
#pragma unroll
  for (int j = 0; j < 8; j++) ones[j] = (__bf16)1.0f;
  floatx4 o[2][8] = {};
  floatx4 lsum[2] = {};
  const int nblocks = (tile + 2) >> 1;  // ceil((q0+32)/64)

  stage(0, 0);
  __syncthreads();  // buf0 staged (compiler drains vmcnt before barrier)

  for (int it = 0; it < nblocks; it++) {
    const int cur = it & 1;
    const int s0 = it * 64;
    if (it + 1 < nblocks) stage(cur ^ 1, s0 + 64);  // prefetch next, other buffer
    // QK^T: 32 q rows x 64 keys (K-frags shared by both m-tiles)
    floatx4 sacc[2][4] = {};
#pragma unroll
    for (int kc = 0; kc < 4; kc++) {
      bf16x8 bfr[4];
#pragma unroll
      for (int nt = 0; nt < 4; nt++) {
        int key = nt * 16 + l16;
        int seg = (kc * 4 + quad) ^ (key & 7);
        bfr[nt] = *(const bf16x8*)&Ks[cur][key][seg * 8];
      }
#pragma unroll
      for (int mt = 0; mt < 2; mt++)
#pragma unroll
        for (int nt = 0; nt < 4; nt++)
          sacc[mt][nt] = MFMA16x16x32(qf[mt][kc], bfr[nt], sacc[mt][nt], 0, 0, 0);
    }
    // P = exp(S*scale), masked on diagonal block(s)
    const bool diag = (it == nblocks - 1);
#pragma unroll
    for (int mt = 0; mt < 2; mt++)
#pragma unroll
      for (int r = 0; r < 4; r++) {
        const int row = quad * 4 + r;
        const int qg = q0 + mt * 16 + row;
#pragma unroll
        for (int nt = 0; nt < 4; nt++) {
          float p = __builtin_exp2f(sacc[mt][nt][r] * cexp);
          if (diag) { int keyg = s0 + nt * 16 + l16; p = (keyg <= qg) ? p : 0.f; }
          int col = nt * 16 + l16;
          Ps[wave][mt][row][(((col >> 3) ^ (row & 7)) << 3) + (col & 7)] = (__bf16)p;
        }
      }
    // P @ V (+ ones for row sums). Same-wave Ps write->read: no barrier.
#pragma unroll
    for (int c2 = 0; c2 < 2; c2++) {
      bf16x8 pa[2];
#pragma unroll
      for (int mt = 0; mt < 2; mt++) {
        int segp = ((c2 * 4 + quad) ^ (l16 & 7)) << 3;
        pa[mt] = *(const bf16x8*)&Ps[wave][mt][l16][segp];
        lsum[mt] = MFMA16x16x32(pa[mt], ones, lsum[mt], 0, 0, 0);
      }
#pragma unroll
      for (int dt = 0; dt < 8; dt++) {
        int row = dt * 16 + l16;
        int seg = (c2 * 4 + quad) ^ (row & 7);
        bf16x8 vf = *(const bf16x8*)&Vt[cur][row][seg * 8];
#pragma unroll
        for (int mt = 0; mt < 2; mt++)
          o[mt][dt] = MFMA16x16x32(pa[mt], vf, o[mt][dt], 0, 0, 0);
      }
    }
    __syncthreads();  // drains prefetch DMA; frees buf `cur` for iter it+1's prefetch
  }
#pragma unroll
  for (int mt = 0; mt < 2; mt++) {
    float inv[4];
#pragma unroll
    for (int r = 0; r < 4; r++) inv[r] = 1.f / lsum[mt][r];
#pragma unroll
    for (int dt = 0; dt < 8; dt++)
#pragma unroll
      for (int r = 0; r < 4; r++) {
        int qg = q0 + mt * 16 + quad * 4 + r;
        yb[(size_t)(b * 2048 + qg) * 2048 + h * 128 + dt * 16 + l16] =
            (__bf16)(o[mt][dt][r] * inv[r]);
      }
  }
}

// ---------------- host ----------------
extern "C" void kernel_launch(void* const* d_in, const int* in_sizes, int n_in,
                              void* d_out, int out_size, void* d_ws, size_t ws_size,
                              hipStream_t stream) {
  const float* x  = (const float*)d_in[0];
  const float* fc = (const float*)d_in[1];
  const float* fs = (const float*)d_in[2];
  const float* wq = (const float*)d_in[3];
  const float* wk = (const float*)d_in[4];
  const float* wv = (const float*)d_in[5];
  const float* wo = (const float*)d_in[6];
  float* out = (float*)d_out;
  char* ws = (char*)d_ws;

  __bf16* xb   = (__bf16*)(ws);              // 4096x2048 bf16
  __bf16* wqkv = (__bf16*)(ws + 16777216);   // 3072x2048 bf16 (wq|wk|wv)
  __bf16* wob  = (__bf16*)(ws + 29360128);   // 2048x2048 bf16
  __bf16* qbuf = (__bf16*)(ws + 37748736);   // 4096x2048 bf16 (roped)
  __bf16* kbuf = (__bf16*)(ws + 54525952);   // 4096x512 bf16 (roped)
  __bf16* vtg  = (__bf16*)(ws + 58720256);   // 1024x2048 bf16 (V^T per b,kvh)
  __bf16* ybuf = (__bf16*)(ws + 62914560);   // 4096x2048 bf16

  // one merged cast launch (dst regions contiguous from ws+0)
  cast_all_kernel<<<18432, 256, 0, stream>>>(x, wq, wk, wv, wo, xb);

  // QKV projection with fused RoPE + transposed-V epilogue (M=4096, N=3072, K=2048)
  gemm_bt<1><<<dim3(24, 32), 256, 0, stream>>>(xb, wqkv, nullptr, fc, fs,
                                               qbuf, kbuf, vtg, 4096, 3072, 2048);

  // flash attention: 512 4-wave WGs, 32 q-rows/wave, double-buffered K/V
  attn_kernel<<<dim3(512), 256, 0, stream>>>(qbuf, kbuf, vtg, ybuf);

  // output projection: out = y @ wo^T (M=4096, N=2048, K=2048)
  gemm_bt<0><<<dim3(16, 32), 256, 0, stream>>>(ybuf, wob, out, nullptr, nullptr,
                                               nullptr, nullptr, nullptr, 4096, 2048, 2048);
}